// Round 6
// baseline (1044.007 us; speedup 1.0000x reference)
//
#include <hip/hip_runtime.h>
#include <hip/hip_bf16.h>

typedef __attribute__((ext_vector_type(8))) short bf16x8;
typedef __attribute__((ext_vector_type(4))) float f32x4;
typedef __attribute__((ext_vector_type(4))) int   i32x4;
typedef __attribute__((ext_vector_type(4))) unsigned short u16x4;
typedef unsigned short u16;

#define G_ 20000
#define B_ 512

__device__ __forceinline__ u16 f2bf(float x) {
  __hip_bfloat16 h = __float2bfloat16(x);   // RTN
  return __builtin_bit_cast(u16, h);
}

__device__ __forceinline__ void glds16(const void* g, void* l) {
  __builtin_amdgcn_global_load_lds(
      (const __attribute__((address_space(1))) void*)g,
      (__attribute__((address_space(3))) void*)l, 16, 0, 0);
}

// swizzled u16 index for logical (row b, col kk in [0,64)) within a slab
__device__ __forceinline__ int swz(int b, int kk) {
  return b * 64 + ((((kk >> 3) & 7) ^ (b & 7)) << 3) + (kk & 7);
}

// ---------------------------------------------------------------------------
// K1: per-gene micro-MLP -> X slabs [slab][512][64] bf16, chunk-swizzled.
// reps: idempotent repetition for profiling visibility (identical writes).
// ---------------------------------------------------------------------------
__global__ void k_gene(const float* __restrict__ expr,
                       const float* __restrict__ bw1, const float* __restrict__ bb1,
                       const float* __restrict__ bw2, const float* __restrict__ bb2,
                       const float* __restrict__ gw,  const float* __restrict__ gb,
                       const int* __restrict__ cc, const float* __restrict__ cnc,
                       const float* __restrict__ race, const float* __restrict__ eth,
                       const float* __restrict__ inter, const float* __restrict__ prot,
                       const float* __restrict__ mw, const float* __restrict__ mb,
                       u16* __restrict__ Xt, int reps) {
  int b0 = blockIdx.y * 32;

  if (blockIdx.x == 79) {
    for (int rep = 0; rep < reps; ++rep) {
      int b = b0 + (threadIdx.x >> 3);
      int j0 = (threadIdx.x & 7) * 12;
      int c0 = cc[b * 3], c1 = cc[b * 3 + 1], c2 = cc[b * 3 + 2];
      float nc[10];
      #pragma unroll
      for (int v = 0; v < 10; ++v)
        nc[v] = fmaxf(cnc[b * 20 + v] * mw[v * 2] + cnc[b * 20 + 10 + v] * mw[v * 2 + 1] + mb[v], 0.f);
      #pragma unroll
      for (int jj = 0; jj < 12; ++jj) {
        int j = j0 + jj;
        float v;
        if (j < 8)       v = race[c0 * 8 + j];
        else if (j < 12) v = eth[c1 * 4 + (j - 8)];
        else if (j < 20) v = inter[(c0 * 4 + c1) * 8 + (j - 12)];
        else if (j < 28) v = prot[c2 * 8 + (j - 20)];
        else if (j < 38) v = nc[j - 28];
        else             v = 0.f;
        int k = 20000 + j;
        Xt[(size_t)(k >> 6) * 32768 + swz(b, k & 63)] = f2bf(v);
      }
      asm volatile("" ::: "memory");
    }
    return;
  }

  int g = blockIdx.x * 256 + threadIdx.x;
  if (g >= G_) return;

  for (int rep = 0; rep < reps; ++rep) {
    f32x4 w1a = ((const f32x4*)bw1)[g];
    f32x4 w1b = ((const f32x4*)bw1)[G_ + g];
    f32x4 b1a = ((const f32x4*)bb1)[g];
    f32x4 b1b = ((const f32x4*)bb1)[G_ + g];
    f32x4 w2a = ((const f32x4*)bw2)[g];
    f32x4 w2b = ((const f32x4*)bw2)[G_ + g];
    float bb2a = bb2[g], bb2b = bb2[G_ + g];
    float gw0 = gw[g * 2], gw1 = gw[g * 2 + 1];
    float gbg = gb[g];

    u16* slab = Xt + (size_t)(g >> 6) * 32768;
    int kk = g & 63, ch = (kk >> 3) & 7, klo = kk & 7;

    #pragma unroll 4
    for (int b = b0; b < b0 + 32; ++b) {
      float x0 = expr[(size_t)(b * 2) * G_ + g];
      float x1 = expr[(size_t)(b * 2 + 1) * G_ + g];
      float h0 = fmaxf(x0 * w1a.x + b1a.x, 0.f);
      float h1 = fmaxf(x0 * w1a.y + b1a.y, 0.f);
      float h2 = fmaxf(x0 * w1a.z + b1a.z, 0.f);
      float h3 = fmaxf(x0 * w1a.w + b1a.w, 0.f);
      float s0 = fmaxf(h0 * w2a.x + h1 * w2a.y + h2 * w2a.z + h3 * w2a.w + bb2a, 0.f);
      float g0 = fmaxf(x1 * w1b.x + b1b.x, 0.f);
      float g1 = fmaxf(x1 * w1b.y + b1b.y, 0.f);
      float g2 = fmaxf(x1 * w1b.z + b1b.z, 0.f);
      float g3 = fmaxf(x1 * w1b.w + b1b.w, 0.f);
      float s1 = fmaxf(g0 * w2b.x + g1 * w2b.y + g2 * w2b.z + g3 * w2b.w + bb2b, 0.f);
      float e = fmaxf(s0 * gw0 + s1 * gw1 + gbg, 0.f);
      slab[b * 64 + ((ch ^ (b & 7)) << 3) + klo] = f2bf(e);
    }
    asm volatile("" ::: "memory");
  }
}

// ---------------------------------------------------------------------------
// GEMM: BM=512 BN=64 BK=64, 8 waves (wave-tile 64x64), 72 KB LDS -> 2 blk/CU.
// reps: idempotent repetition (re-zeroes acc, redoes K-loop, re-stores).
// ---------------------------------------------------------------------------
__global__ __launch_bounds__(512, 4) void k_gemm(
    const u16* __restrict__ Xt, const float* __restrict__ W,
    float* __restrict__ part, int nSlabs, int Kvalid, int Nvalid, int Npad,
    int reps) {
  __shared__ __align__(16) u16 As[512 * 64];   // 64 KB (swizzled image)
  __shared__ __align__(16) u16 Bs[64 * 64];    // 8 KB, [n][k] swizzled

  const int tid = threadIdx.x;
  const int nt = blockIdx.x, split = blockIdx.y, S = gridDim.y;
  const int n0 = nt * 64;
  const int s0 = (int)(((long)split * nSlabs) / S);
  const int s1 = (int)(((long)(split + 1) * nSlabs) / S);
  const int sLast = s1 - 1;

  const int lane = tid & 63, wv = tid >> 6;
  const int l15 = lane & 15, l4 = lane >> 4;
  const int bn = lane;                 // B staging: col
  const int bh = wv;                   // k-octant
  const int nW = n0 + bn;
  const bool nok = nW < Nvalid;

  for (int rep = 0; rep < reps; ++rep) {
    f32x4 acc[4][4];
    #pragma unroll
    for (int i = 0; i < 4; ++i)
      #pragma unroll
      for (int j = 0; j < 4; ++j)
        acc[i][j] = f32x4{0.f, 0.f, 0.f, 0.f};

    float wreg[8];

    auto GLDS = [&](int s) {
      const char* sb = (const char*)(Xt + (size_t)s * 32768);
      char* lb = (char*)&As[0];
      #pragma unroll
      for (int j = 0; j < 8; ++j) {
        int q = wv * 8 + j;
        glds16(sb + q * 1024 + lane * 16, lb + q * 1024);
      }
    };
    auto WLOAD = [&](int s) {
      int kb = s * 64 + bh * 8;
      #pragma unroll
      for (int j = 0; j < 8; ++j) {
        int k = kb + j;
        wreg[j] = (nok && k < Kvalid) ? W[(size_t)k * Nvalid + nW] : 0.f;
      }
    };
    auto BSTORE = [&]() {
      i32x4 pk;
      #pragma unroll
      for (int q = 0; q < 4; ++q) {
        u16 lo = f2bf(wreg[q * 2]);
        u16 hi = f2bf(wreg[q * 2 + 1]);
        pk[q] = (int)(unsigned)lo | ((int)(unsigned)hi << 16);
      }
      *(i32x4*)&Bs[bn * 64 + ((bh ^ (bn & 7)) << 3)] = pk;
    };
    auto COMPUTE = [&]() {
      #pragma unroll
      for (int kk = 0; kk < 2; ++kk) {
        bf16x8 bfr[4];
        #pragma unroll
        for (int nf = 0; nf < 4; ++nf) {
          int n = nf * 16 + l15;
          int cch = kk * 4 + l4;
          bfr[nf] = *(const bf16x8*)&Bs[n * 64 + ((cch ^ (n & 7)) << 3)];
        }
        #pragma unroll
        for (int mf = 0; mf < 4; ++mf) {
          int m = wv * 64 + mf * 16 + l15;
          int cch = kk * 4 + l4;
          bf16x8 af = *(const bf16x8*)&As[m * 64 + ((cch ^ (m & 7)) << 3)];
          #pragma unroll
          for (int nf = 0; nf < 4; ++nf)
            acc[mf][nf] = __builtin_amdgcn_mfma_f32_16x16x32_bf16(af, bfr[nf], acc[mf][nf], 0, 0, 0);
        }
      }
    };

    // prologue
    GLDS(s0); WLOAD(s0);
    BSTORE();                               // waits W(s0) (drains glds too)
    WLOAD((s0 + 1 > sLast) ? sLast : s0 + 1);
    asm volatile("s_waitcnt vmcnt(8) lgkmcnt(0)" ::: "memory");
    __builtin_amdgcn_s_barrier();

    for (int s = s0; s < s1; ++s) {
      COMPUTE();
      __builtin_amdgcn_s_barrier();
      if (s + 1 <= sLast) {
        GLDS(s + 1);
        BSTORE();                           // wreg = W(s+1), landed during COMPUTE
        WLOAD((s + 2 > sLast) ? sLast : s + 2);
        asm volatile("s_waitcnt vmcnt(8) lgkmcnt(0)" ::: "memory");
        __builtin_amdgcn_s_barrier();
      }
    }

    float* outp = part + (size_t)split * B_ * Npad;
    #pragma unroll
    for (int mf = 0; mf < 4; ++mf)
      #pragma unroll
      for (int nf = 0; nf < 4; ++nf) {
        int col = n0 + nf * 16 + l15;
        int rb = wv * 64 + mf * 16 + l4 * 4;
        #pragma unroll
        for (int r = 0; r < 4; ++r)
          outp[(size_t)(rb + r) * Npad + col] = acc[mf][nf][r];
      }
    asm volatile("" ::: "memory");
    if (rep + 1 < reps) __builtin_amdgcn_s_barrier();
  }
}

// ---------------------------------------------------------------------------
// Reduce split-K partials + bias + ReLU -> bf16 swizzled slab activations
// ---------------------------------------------------------------------------
__global__ void k_reduce(const float* __restrict__ part, const float* __restrict__ bias,
                         u16* __restrict__ Ht, int S, int Npad, int Nout, int Nvalid) {
  int idx = blockIdx.x * 256 + threadIdx.x;
  int perRow = Nout >> 2;
  if (idx >= B_ * perRow) return;
  int b = idx / perRow;
  int n = (idx - b * perRow) * 4;
  float v[4] = {0.f, 0.f, 0.f, 0.f};
  for (int s = 0; s < S; ++s) {
    const f32x4 p = *(const f32x4*)&part[(size_t)s * B_ * Npad + (size_t)b * Npad + n];
    #pragma unroll
    for (int r = 0; r < 4; ++r) v[r] += p[r];
  }
  u16x4 o;
  #pragma unroll
  for (int r = 0; r < 4; ++r) {
    float bi = (n + r < Nvalid) ? bias[n + r] : 0.f;
    o[r] = f2bf(fmaxf(v[r] + bi, 0.f));
  }
  *(u16x4*)&Ht[(size_t)(n >> 6) * 32768 + swz(b, n & 63)] = o;
}

// ---------------------------------------------------------------------------
// Fused tail: reduce L2 partials (+bias+relu) -> L3 (313->78) -> L4 (78->2)
// ---------------------------------------------------------------------------
__global__ void k_tail(const float* __restrict__ part2, const float* __restrict__ b2,
                       const float* __restrict__ W3, const float* __restrict__ b3,
                       const float* __restrict__ W4, const float* __restrict__ b4,
                       int S2, int Npad2, float* __restrict__ out) {
  __shared__ float h3[320];
  __shared__ float h4[80];
  int b = blockIdx.x, tid = threadIdx.x;  // 128 threads
  for (int n = tid; n < 320; n += 128) {
    float v = 0.f;
    for (int s = 0; s < S2; ++s)
      v += part2[(size_t)s * B_ * Npad2 + (size_t)b * Npad2 + n];
    float bi = (n < 313) ? b2[n] : 0.f;
    h3[n] = fmaxf(v + bi, 0.f);
  }
  __syncthreads();
  if (tid < 78) {
    float a = b3[tid];
    #pragma unroll 4
    for (int k = 0; k < 313; ++k) a += h3[k] * W3[k * 78 + tid];
    h4[tid] = fmaxf(a, 0.f);
  }
  __syncthreads();
  if (tid < 2) {
    float a = b4[tid];
    for (int k = 0; k < 78; ++k) a += h4[k] * W4[k * 2 + tid];
    out[b * 2 + tid] = a;
  }
}

// ---------------------------------------------------------------------------
extern "C" void kernel_launch(void* const* d_in, const int* in_sizes, int n_in,
                              void* d_out, int out_size, void* d_ws, size_t ws_size,
                              hipStream_t stream) {
  const float* expr = (const float*)d_in[0];
  const int*   cc   = (const int*)d_in[1];
  const float* cnc  = (const float*)d_in[2];
  const float* bw1  = (const float*)d_in[3];
  const float* bb1  = (const float*)d_in[4];
  const float* bw2  = (const float*)d_in[5];
  const float* bb2  = (const float*)d_in[6];
  const float* gw   = (const float*)d_in[7];
  const float* gb   = (const float*)d_in[8];
  const float* race = (const float*)d_in[9];
  const float* eth  = (const float*)d_in[10];
  const float* inter= (const float*)d_in[11];
  const float* prot = (const float*)d_in[12];
  const float* mw   = (const float*)d_in[13];
  const float* mb   = (const float*)d_in[14];
  const float* w0 = (const float*)d_in[15]; const float* b0 = (const float*)d_in[16];
  const float* w1 = (const float*)d_in[17]; const float* b1 = (const float*)d_in[18];
  const float* w2 = (const float*)d_in[19]; const float* b2 = (const float*)d_in[20];
  const float* w3 = (const float*)d_in[21]; const float* b3 = (const float*)d_in[22];
  const float* w4 = (const float*)d_in[23]; const float* b4 = (const float*)d_in[24];

  u16* Xt  = (u16*)d_ws;
  u16* H1t = Xt  + (size_t)314 * 32768;
  u16* H2t = H1t + (size_t)80 * 32768;
  float* part = (float*)(H2t + (size_t)20 * 32768);

  // DIAGNOSTIC ROUND: k_gene reps=6, L0 k_gemm reps=4 (idempotent) so both
  // dispatches exceed the 235-us poison-fills and surface in top-5 counters.
  k_gene<<<dim3(80, 16), 256, 0, stream>>>(expr, bw1, bb1, bw2, bb2, gw, gb,
                                           cc, cnc, race, eth, inter, prot, mw, mb,
                                           Xt, 6);

  // L0: (512 x 20038) @ (20038 x 5009), 314 slabs, BN=64, split-K=6, x4 reps
  k_gemm<<<dim3(80, 6), 512, 0, stream>>>(Xt, w0, part, 314, 20038, 5009, 5120, 4);
  k_reduce<<<2560, 256, 0, stream>>>(part, b0, H1t, 6, 5120, 5120, 5009);

  // L1: (512 x 5009) @ (5009 x 1252), 80 slabs, BN=64, split-K=8
  k_gemm<<<dim3(20, 8), 512, 0, stream>>>(H1t, w1, part, 80, 5009, 1252, 1280, 1);
  k_reduce<<<640, 256, 0, stream>>>(part, b1, H2t, 8, 1280, 1280, 1252);

  // L2: (512 x 1252) @ (1252 x 313), 20 slabs, BN=64, split-K=5
  k_gemm<<<dim3(6, 5), 512, 0, stream>>>(H2t, w2, part, 20, 1252, 313, 384, 1);

  // fused reduce(L2) + L3 + L4 tail
  k_tail<<<512, 128, 0, stream>>>(part, b2, w3, b3, w4, b4, 5, 384, (float*)d_out);
}

// Round 7
// 319.697 us; speedup vs baseline: 3.2656x; 3.2656x over previous
//
#include <hip/hip_runtime.h>
#include <hip/hip_bf16.h>

typedef __attribute__((ext_vector_type(8))) short bf16x8;
typedef __attribute__((ext_vector_type(4))) float f32x4;
typedef __attribute__((ext_vector_type(4))) int   i32x4;
typedef __attribute__((ext_vector_type(4))) unsigned short u16x4;
typedef unsigned short u16;
typedef unsigned long long ull;

#define G_ 20000
#define B_ 512
#define SLAB_U16 16384   // one K=32 slab: [4 chunks][512 rows][8 u16] = 32 KB

__device__ __forceinline__ u16 f2bf(float x) {
  __hip_bfloat16 h = __float2bfloat16(x);   // RTN
  return __builtin_bit_cast(u16, h);
}

__device__ __forceinline__ void glds16(const void* g, void* l) {
  __builtin_amdgcn_global_load_lds(
      (const __attribute__((address_space(1))) void*)g,
      (__attribute__((address_space(3))) void*)l, 16, 0, 0);
}

// within-slab u16 index for logical (row b, col kk in [0,32)):
// layout [chunk=kk>>3][row][kk&7] -> 16 consecutive rows are 256 B contiguous
__device__ __forceinline__ int aidx(int b, int kk) {
  return ((kk >> 3) & 3) * 4096 + b * 8 + (kk & 7);
}

// ---------------------------------------------------------------------------
// K1: per-gene micro-MLP -> X slabs (chunked layout), cols 0..19999.
// blockIdx.x==79 handles clinical cols 20000..20095 (38 real + zero pad).
// ---------------------------------------------------------------------------
__global__ void k_gene(const float* __restrict__ expr,
                       const float* __restrict__ bw1, const float* __restrict__ bb1,
                       const float* __restrict__ bw2, const float* __restrict__ bb2,
                       const float* __restrict__ gw,  const float* __restrict__ gb,
                       const int* __restrict__ cc, const float* __restrict__ cnc,
                       const float* __restrict__ race, const float* __restrict__ eth,
                       const float* __restrict__ inter, const float* __restrict__ prot,
                       const float* __restrict__ mw, const float* __restrict__ mb,
                       u16* __restrict__ Xt) {
  int b0 = blockIdx.y * 32;

  if (blockIdx.x == 79) {
    int b = b0 + (threadIdx.x >> 3);
    int j0 = (threadIdx.x & 7) * 12;
    int c0 = cc[b * 3], c1 = cc[b * 3 + 1], c2 = cc[b * 3 + 2];
    float nc[10];
    #pragma unroll
    for (int v = 0; v < 10; ++v)
      nc[v] = fmaxf(cnc[b * 20 + v] * mw[v * 2] + cnc[b * 20 + 10 + v] * mw[v * 2 + 1] + mb[v], 0.f);
    #pragma unroll
    for (int jj = 0; jj < 12; ++jj) {
      int j = j0 + jj;
      float v;
      if (j < 8)       v = race[c0 * 8 + j];
      else if (j < 12) v = eth[c1 * 4 + (j - 8)];
      else if (j < 20) v = inter[(c0 * 4 + c1) * 8 + (j - 12)];
      else if (j < 28) v = prot[c2 * 8 + (j - 20)];
      else if (j < 38) v = nc[j - 28];
      else             v = 0.f;
      int k = 20000 + j;
      Xt[(size_t)(k >> 5) * SLAB_U16 + aidx(b, k & 31)] = f2bf(v);
    }
    return;
  }

  int g = blockIdx.x * 256 + threadIdx.x;
  if (g >= G_) return;

  f32x4 w1a = ((const f32x4*)bw1)[g];
  f32x4 w1b = ((const f32x4*)bw1)[G_ + g];
  f32x4 b1a = ((const f32x4*)bb1)[g];
  f32x4 b1b = ((const f32x4*)bb1)[G_ + g];
  f32x4 w2a = ((const f32x4*)bw2)[g];
  f32x4 w2b = ((const f32x4*)bw2)[G_ + g];
  float bb2a = bb2[g], bb2b = bb2[G_ + g];
  float gw0 = gw[g * 2], gw1 = gw[g * 2 + 1];
  float gbg = gb[g];

  u16* slab = Xt + (size_t)(g >> 5) * SLAB_U16;
  int co = ((g >> 3) & 3) * 4096 + (g & 7);   // chunk base + in-chunk offset

  #pragma unroll 4
  for (int b = b0; b < b0 + 32; ++b) {
    float x0 = expr[(size_t)(b * 2) * G_ + g];
    float x1 = expr[(size_t)(b * 2 + 1) * G_ + g];
    float h0 = fmaxf(x0 * w1a.x + b1a.x, 0.f);
    float h1 = fmaxf(x0 * w1a.y + b1a.y, 0.f);
    float h2 = fmaxf(x0 * w1a.z + b1a.z, 0.f);
    float h3 = fmaxf(x0 * w1a.w + b1a.w, 0.f);
    float s0 = fmaxf(h0 * w2a.x + h1 * w2a.y + h2 * w2a.z + h3 * w2a.w + bb2a, 0.f);
    float g0 = fmaxf(x1 * w1b.x + b1b.x, 0.f);
    float g1 = fmaxf(x1 * w1b.y + b1b.y, 0.f);
    float g2 = fmaxf(x1 * w1b.z + b1b.z, 0.f);
    float g3 = fmaxf(x1 * w1b.w + b1b.w, 0.f);
    float s1 = fmaxf(g0 * w2b.x + g1 * w2b.y + g2 * w2b.z + g3 * w2b.w + bb2b, 0.f);
    float e = fmaxf(s0 * gw0 + s1 * gw1 + gbg, 0.f);
    slab[co + b * 8] = f2bf(e);
  }
}

// ---------------------------------------------------------------------------
// GEMM: BM=512 BN=64 BK=32, 8 waves (wave-tile 64x64), LDS 72 KB -> 2 blk/CU.
// Double-buffered A (glds, chunked layout) and B (reg->bf16->LDS).
// Every vmcnt wait targets loads issued one full iteration earlier.
// ---------------------------------------------------------------------------
__global__ __launch_bounds__(512, 4) void k_gemm(
    const u16* __restrict__ Xt, const float* __restrict__ W,
    float* __restrict__ part, int nSlabs, int Kvalid, int Nvalid, int Npad) {
  __shared__ __align__(16) u16 As[2][SLAB_U16];  // 2 x 32 KB
  __shared__ __align__(16) u16 Bs[2][2048];      // 2 x 4 KB, [4][64][8]

  const int tid = threadIdx.x;
  const int nt = blockIdx.x, split = blockIdx.y, S = gridDim.y;
  const int n0 = nt * 64;
  const int s0 = (int)(((long)split * nSlabs) / S);
  const int s1 = (int)(((long)(split + 1) * nSlabs) / S);
  const int sLast = s1 - 1;

  const int lane = tid & 63, wv = tid >> 6;
  const int l15 = lane & 15, l4 = lane >> 4;
  const int bn = lane, bh = wv;        // W staging: col, k-quad
  const int nW = n0 + bn;
  const bool nok = nW < Nvalid;

  f32x4 acc[4][4];
  #pragma unroll
  for (int i = 0; i < 4; ++i)
    #pragma unroll
    for (int j = 0; j < 4; ++j) acc[i][j] = f32x4{0.f, 0.f, 0.f, 0.f};

  float wreg[4];

  auto GLDS = [&](int s, int buf) {
    const char* sb = (const char*)(Xt + (size_t)s * SLAB_U16);
    char* lb = (char*)&As[buf][0];
    #pragma unroll
    for (int j = 0; j < 4; ++j) {
      int q = wv * 4 + j;                       // 1-KB unit, wave-uniform dest
      glds16(sb + q * 1024 + lane * 16, lb + q * 1024);
    }
  };
  auto WLOAD = [&](int s) {
    int kb = s * 32 + bh * 4;
    #pragma unroll
    for (int j = 0; j < 4; ++j) {
      int k = kb + j;
      wreg[j] = (nok && k < Kvalid) ? W[(size_t)k * Nvalid + nW] : 0.f;
    }
  };
  auto BSTORE = [&](int buf) {
    unsigned p0 = (unsigned)f2bf(wreg[0]) | ((unsigned)f2bf(wreg[1]) << 16);
    unsigned p1 = (unsigned)f2bf(wreg[2]) | ((unsigned)f2bf(wreg[3]) << 16);
    int idx = (bh >> 1) * 512 + bn * 8 + (bh & 1) * 4;   // [chunk][n][off]
    *(ull*)&Bs[buf][idx] = ((ull)p1 << 32) | (ull)p0;
  };
  auto COMPUTE = [&](int buf) {
    bf16x8 bfr[4];
    #pragma unroll
    for (int nf = 0; nf < 4; ++nf)
      bfr[nf] = *(const bf16x8*)&Bs[buf][l4 * 512 + (nf * 16 + l15) * 8];
    #pragma unroll
    for (int mf = 0; mf < 4; ++mf) {
      bf16x8 af = *(const bf16x8*)&As[buf][l4 * 4096 + (wv * 64 + mf * 16 + l15) * 8];
      #pragma unroll
      for (int nf = 0; nf < 4; ++nf)
        acc[mf][nf] = __builtin_amdgcn_mfma_f32_16x16x32_bf16(af, bfr[nf], acc[mf][nf], 0, 0, 0);
    }
  };

  // prologue: stage slab s0 into buf0; leave A(s0+1),W(s0+1) in flight
  GLDS(s0, 0); WLOAD(s0);
  asm volatile("s_waitcnt vmcnt(0)" ::: "memory");
  BSTORE(0);
  int sn = (s0 + 1 > sLast) ? sLast : s0 + 1;
  GLDS(sn, 1); WLOAD(sn);               // in flight: A(s+1)x4, W(s+1)x4
  asm volatile("s_waitcnt lgkmcnt(0)" ::: "memory");
  __builtin_amdgcn_s_barrier();

  int c = 0;
  for (int s = s0; s < s1; ++s) {
    COMPUTE(c);                          // reads As[c], Bs[c]
    if (s < sLast) {
      __builtin_amdgcn_s_barrier();      // all waves done reading As[c], Bs[c]
      int sp = (s + 2 > sLast) ? sLast : s + 2;
      GLDS(sp, c);                       // refill freed buffer; stays in flight
      // queue: [A(s+1)x4 old, W(s+1)x4 old, A(s+2)x4 new] -> retire oldest 8
      asm volatile("s_waitcnt vmcnt(4)" ::: "memory");
      BSTORE(c ^ 1);                     // Bs[c^1] = B(s+1) from landed wreg
      WLOAD(sp);                         // prefetch W(s+2), streams under compute
      asm volatile("s_waitcnt lgkmcnt(0)" ::: "memory");
      __builtin_amdgcn_s_barrier();      // A(s+1) (all waves waited), B(s+1) ready
      c ^= 1;
    }
  }
  asm volatile("s_waitcnt vmcnt(0)" ::: "memory");  // drain glds before exit

  float* outp = part + (size_t)split * B_ * Npad;
  #pragma unroll
  for (int mf = 0; mf < 4; ++mf)
    #pragma unroll
    for (int nf = 0; nf < 4; ++nf) {
      int col = n0 + nf * 16 + l15;
      int rb = wv * 64 + mf * 16 + l4 * 4;
      #pragma unroll
      for (int r = 0; r < 4; ++r)
        outp[(size_t)(rb + r) * Npad + col] = acc[mf][nf][r];
    }
}

// ---------------------------------------------------------------------------
// Reduce split-K partials + bias + ReLU -> bf16 chunked slab activations
// ---------------------------------------------------------------------------
__global__ void k_reduce(const float* __restrict__ part, const float* __restrict__ bias,
                         u16* __restrict__ Ht, int S, int Npad, int Nout, int Nvalid) {
  int idx = blockIdx.x * 256 + threadIdx.x;
  int perRow = Nout >> 2;
  if (idx >= B_ * perRow) return;
  int b = idx / perRow;
  int n = (idx - b * perRow) * 4;
  float v[4] = {0.f, 0.f, 0.f, 0.f};
  for (int s = 0; s < S; ++s) {
    const f32x4 p = *(const f32x4*)&part[(size_t)s * B_ * Npad + (size_t)b * Npad + n];
    #pragma unroll
    for (int r = 0; r < 4; ++r) v[r] += p[r];
  }
  u16x4 o;
  #pragma unroll
  for (int r = 0; r < 4; ++r) {
    float bi = (n + r < Nvalid) ? bias[n + r] : 0.f;
    o[r] = f2bf(fmaxf(v[r] + bi, 0.f));
  }
  // n%4==0 -> 4 u16 contiguous inside one 8-u16 in-chunk row (n&7 in {0,4})
  *(u16x4*)&Ht[(size_t)(n >> 5) * SLAB_U16 + aidx(b, n & 31)] = o;
}

// ---------------------------------------------------------------------------
// Fused tail: reduce L2 partials (+bias+relu) -> L3 (313->78) -> L4 (78->2)
// ---------------------------------------------------------------------------
__global__ void k_tail(const float* __restrict__ part2, const float* __restrict__ b2,
                       const float* __restrict__ W3, const float* __restrict__ b3,
                       const float* __restrict__ W4, const float* __restrict__ b4,
                       int S2, int Npad2, float* __restrict__ out) {
  __shared__ float h3[320];
  __shared__ float h4[80];
  int b = blockIdx.x, tid = threadIdx.x;  // 128 threads
  for (int n = tid; n < 320; n += 128) {
    float v = 0.f;
    for (int s = 0; s < S2; ++s)
      v += part2[(size_t)s * B_ * Npad2 + (size_t)b * Npad2 + n];
    float bi = (n < 313) ? b2[n] : 0.f;
    h3[n] = fmaxf(v + bi, 0.f);
  }
  __syncthreads();
  if (tid < 78) {
    float a = b3[tid];
    #pragma unroll 4
    for (int k = 0; k < 313; ++k) a += h3[k] * W3[k * 78 + tid];
    h4[tid] = fmaxf(a, 0.f);
  }
  __syncthreads();
  if (tid < 2) {
    float a = b4[tid];
    for (int k = 0; k < 78; ++k) a += h4[k] * W4[k * 2 + tid];
    out[b * 2 + tid] = a;
  }
}

// ---------------------------------------------------------------------------
extern "C" void kernel_launch(void* const* d_in, const int* in_sizes, int n_in,
                              void* d_out, int out_size, void* d_ws, size_t ws_size,
                              hipStream_t stream) {
  const float* expr = (const float*)d_in[0];
  const int*   cc   = (const int*)d_in[1];
  const float* cnc  = (const float*)d_in[2];
  const float* bw1  = (const float*)d_in[3];
  const float* bb1  = (const float*)d_in[4];
  const float* bw2  = (const float*)d_in[5];
  const float* bb2  = (const float*)d_in[6];
  const float* gw   = (const float*)d_in[7];
  const float* gb   = (const float*)d_in[8];
  const float* race = (const float*)d_in[9];
  const float* eth  = (const float*)d_in[10];
  const float* inter= (const float*)d_in[11];
  const float* prot = (const float*)d_in[12];
  const float* mw   = (const float*)d_in[13];
  const float* mb   = (const float*)d_in[14];
  const float* w0 = (const float*)d_in[15]; const float* b0 = (const float*)d_in[16];
  const float* w1 = (const float*)d_in[17]; const float* b1 = (const float*)d_in[18];
  const float* w2 = (const float*)d_in[19]; const float* b2 = (const float*)d_in[20];
  const float* w3 = (const float*)d_in[21]; const float* b3 = (const float*)d_in[22];
  const float* w4 = (const float*)d_in[23]; const float* b4 = (const float*)d_in[24];

  // workspace: Xt 628 slabs (20.1 MB) | H1t 157 (5 MB) | H2t 40 (1.3 MB) | part 63 MB
  u16* Xt  = (u16*)d_ws;
  u16* H1t = Xt  + (size_t)628 * SLAB_U16;
  u16* H2t = H1t + (size_t)157 * SLAB_U16;
  float* part = (float*)(H2t + (size_t)40 * SLAB_U16);

  // gene micro-MLP + clinical -> chunked X slabs (K = 20096 = 628*32)
  k_gene<<<dim3(80, 16), 256, 0, stream>>>(expr, bw1, bb1, bw2, bb2, gw, gb,
                                           cc, cnc, race, eth, inter, prot, mw, mb, Xt);

  // L0: (512 x 20038) @ (20038 x 5009), 628 slabs, split-K=6 -> 480 blocks
  k_gemm<<<dim3(80, 6), 512, 0, stream>>>(Xt, w0, part, 628, 20038, 5009, 5120);
  k_reduce<<<2560, 256, 0, stream>>>(part, b0, H1t, 6, 5120, 5024, 5009);

  // L1: (512 x 5009) @ (5009 x 1252), 157 slabs, split-K=8 -> 160 blocks
  k_gemm<<<dim3(20, 8), 512, 0, stream>>>(H1t, w1, part, 157, 5009, 1252, 1280);
  k_reduce<<<640, 256, 0, stream>>>(part, b1, H2t, 8, 1280, 1280, 1252);

  // L2: (512 x 1252) @ (1252 x 313), 40 slabs, split-K=5 -> 25 blocks
  k_gemm<<<dim3(5, 5), 512, 0, stream>>>(H2t, w2, part, 40, 1252, 313, 320);

  // fused reduce(L2) + L3 + L4 tail
  k_tail<<<512, 128, 0, stream>>>(part, b2, w3, b3, w4, b4, 5, 320, (float*)d_out);
}